// Round 1
// baseline (6828.739 us; speedup 1.0000x reference)
//
#include <hip/hip_runtime.h>
#include <math.h>

// Problem constants (match reference; runtime sizes derived from in_sizes as a check)
#define D_NODE 12
#define D_EDGE 4
#define HID    15
#define HS     16   // padded row stride for hidden/aggr buffers

// ---------------- Layer 0 edge kernel: msg = relu(x[src] + Wec1@attr + bec1), atomic into aggr[dst] (12-dim)
__global__ __launch_bounds__(256) void k_edge0(
    const float* __restrict__ x, const int* __restrict__ ei, long long ne,
    const float* __restrict__ attr,
    const float* __restrict__ Wec1, const float* __restrict__ bec1,
    float* __restrict__ aggr)
{
    __shared__ float sW[48];
    __shared__ float sb[12];
    int t = threadIdx.x;
    if (t < 48) sW[t] = Wec1[t];
    if (t < 12) sb[t] = bec1[t];
    __syncthreads();
    long long e = (long long)blockIdx.x * 256 + t;
    if (e >= ne) return;
    int s = ei[e];
    int d = ei[ne + e];
    float4 a = *reinterpret_cast<const float4*>(attr + e * 4);
    const float4* xs = reinterpret_cast<const float4*>(x + (long long)s * D_NODE);
    float4 x0 = xs[0], x1 = xs[1], x2 = xs[2];
    float xv[12] = {x0.x,x0.y,x0.z,x0.w, x1.x,x1.y,x1.z,x1.w, x2.x,x2.y,x2.z,x2.w};
    float* ag = aggr + (long long)d * D_NODE;
#pragma unroll
    for (int i = 0; i < 12; ++i) {
        float ea = sb[i] + sW[i*4+0]*a.x + sW[i*4+1]*a.y + sW[i*4+2]*a.z + sW[i*4+3]*a.w;
        float m = fmaxf(xv[i] + ea, 0.f);
        atomicAdd(ag + i, m);
    }
}

// ---------------- Layers 1/2 edge kernel: ea2 = Wec2@(Wec1@attr+bec1)+bec2 (recomputed), msg = relu(h[src]+ea2)
__global__ __launch_bounds__(256) void k_edgeK(
    const float* __restrict__ h, const int* __restrict__ ei, long long ne,
    const float* __restrict__ attr,
    const float* __restrict__ Wec1, const float* __restrict__ bec1,
    const float* __restrict__ Wec2, const float* __restrict__ bec2,
    float* __restrict__ aggr)
{
    __shared__ float sW1[48], sb1[12], sW2[180], sb2[15];
    int t = threadIdx.x;
    if (t < 48)  sW1[t] = Wec1[t];
    if (t < 12)  sb1[t] = bec1[t];
    if (t < 180) sW2[t] = Wec2[t];
    if (t < 15)  sb2[t] = bec2[t];
    __syncthreads();
    long long e = (long long)blockIdx.x * 256 + t;
    if (e >= ne) return;
    int s = ei[e];
    int d = ei[ne + e];
    float4 a = *reinterpret_cast<const float4*>(attr + e * 4);
    float ea[12];
#pragma unroll
    for (int i = 0; i < 12; ++i)
        ea[i] = sb1[i] + sW1[i*4+0]*a.x + sW1[i*4+1]*a.y + sW1[i*4+2]*a.z + sW1[i*4+3]*a.w;
    const float4* hs = reinterpret_cast<const float4*>(h + (long long)s * HS);
    float4 h0 = hs[0], h1 = hs[1], h2 = hs[2], h3 = hs[3];
    float hv[16] = {h0.x,h0.y,h0.z,h0.w, h1.x,h1.y,h1.z,h1.w,
                    h2.x,h2.y,h2.z,h2.w, h3.x,h3.y,h3.z,h3.w};
    float* ag = aggr + (long long)d * HS;
#pragma unroll
    for (int i = 0; i < 15; ++i) {
        float e2 = sb2[i];
#pragma unroll
        for (int j = 0; j < 12; ++j) e2 += sW2[i*12+j] * ea[j];
        float m = fmaxf(hv[i] + e2, 0.f);
        atomicAdd(ag + i, m);
    }
}

// ---------------- Node update: hout = elu((hin + aggr) @ W.T + b), padded stride-16 output
template<int IN, int INS>
__global__ __launch_bounds__(256) void k_node(
    const float* __restrict__ hin, const float* __restrict__ aggr, long long nn,
    const float* __restrict__ W, const float* __restrict__ b,
    float* __restrict__ hout)
{
    __shared__ float sW[15 * IN];
    __shared__ float sb[15];
    int t = threadIdx.x;
    for (int i = t; i < 15 * IN; i += 256) sW[i] = W[i];
    if (t < 15) sb[t] = b[t];
    __syncthreads();
    long long n = (long long)blockIdx.x * 256 + t;
    if (n >= nn) return;
    float v[IN];
#pragma unroll
    for (int j = 0; j < IN; ++j)
        v[j] = hin[n * INS + j] + aggr[n * INS + j];
    float* o = hout + n * HS;
#pragma unroll
    for (int i = 0; i < 15; ++i) {
        float acc = sb[i];
#pragma unroll
        for (int j = 0; j < IN; ++j) acc += v[j] * sW[i * IN + j];
        o[i] = acc > 0.f ? acc : expm1f(acc);
    }
    o[15] = 0.f;
}

// ---------------- Pool: pooled[batch[n]] += h[n]  (one thread per (node,feature))
__global__ __launch_bounds__(256) void k_pool(
    const float* __restrict__ h, const int* __restrict__ batch, long long nn,
    float* __restrict__ pooled)
{
    long long idx = (long long)blockIdx.x * 256 + threadIdx.x;
    if (idx >= nn * 15) return;
    long long n = idx / 15;
    int f = (int)(idx - n * 15);
    atomicAdd(&pooled[(long long)batch[n] * HS + f], h[n * HS + f]);
}

// ---------------- Head: out = (pooled @ Wo1.T + bo1) @ Wo2.T + bo2
__global__ __launch_bounds__(256) void k_head(
    const float* __restrict__ pooled, long long ng,
    const float* __restrict__ Wo1, const float* __restrict__ bo1,
    const float* __restrict__ Wo2, const float* __restrict__ bo2,
    float* __restrict__ out)
{
    long long g = (long long)blockIdx.x * 256 + threadIdx.x;
    if (g >= ng) return;
    float p[15], m[15];
#pragma unroll
    for (int j = 0; j < 15; ++j) p[j] = pooled[g * HS + j];
#pragma unroll
    for (int i = 0; i < 15; ++i) {
        float acc = bo1[i];
#pragma unroll
        for (int j = 0; j < 15; ++j) acc += p[j] * Wo1[i * 15 + j];
        m[i] = acc;
    }
#pragma unroll
    for (int i = 0; i < 2; ++i) {
        float acc = bo2[i];
#pragma unroll
        for (int j = 0; j < 15; ++j) acc += m[j] * Wo2[i * 15 + j];
        out[g * 2 + i] = acc;
    }
}

extern "C" void kernel_launch(void* const* d_in, const int* in_sizes, int n_in,
                              void* d_out, int out_size, void* d_ws, size_t ws_size,
                              hipStream_t stream)
{
    const float* x    = (const float*)d_in[0];
    const int*   ei   = (const int*)d_in[1];
    const float* attr = (const float*)d_in[2];
    const int*   batch= (const int*)d_in[3];
    const float* Wec1 = (const float*)d_in[4];
    const float* bec1 = (const float*)d_in[5];
    const float* Wec2 = (const float*)d_in[6];
    const float* bec2 = (const float*)d_in[7];
    const float* Wl0  = (const float*)d_in[8];
    const float* bl0  = (const float*)d_in[9];
    const float* Wl1  = (const float*)d_in[10];
    const float* bl1  = (const float*)d_in[11];
    const float* Wl2  = (const float*)d_in[12];
    const float* bl2  = (const float*)d_in[13];
    const float* Wo1  = (const float*)d_in[14];
    const float* bo1  = (const float*)d_in[15];
    const float* Wo2  = (const float*)d_in[16];
    const float* bo2  = (const float*)d_in[17];

    const long long nn = in_sizes[0] / D_NODE;   // 100000
    const long long ne = in_sizes[1] / 2;        // 3200000
    const long long ng = out_size / 2;           // 1024

    float* ws     = (float*)d_ws;
    float* aggr   = ws;                 // nn*16
    float* hA     = aggr + nn * HS;     // nn*16
    float* hB     = hA   + nn * HS;     // nn*16
    float* pooled = hB   + nn * HS;     // ng*16
    float* out    = (float*)d_out;

    const int eblk = (int)((ne + 255) / 256);
    const int nblk = (int)((nn + 255) / 256);

    // Layer 0 (x: 12-dim, stride 12; aggr: stride 12 region reused)
    hipMemsetAsync(aggr, 0, (size_t)nn * D_NODE * sizeof(float), stream);
    k_edge0<<<eblk, 256, 0, stream>>>(x, ei, ne, attr, Wec1, bec1, aggr);
    k_node<12, 12><<<nblk, 256, 0, stream>>>(x, aggr, nn, Wl0, bl0, hA);

    // Layer 1
    hipMemsetAsync(aggr, 0, (size_t)nn * HS * sizeof(float), stream);
    k_edgeK<<<eblk, 256, 0, stream>>>(hA, ei, ne, attr, Wec1, bec1, Wec2, bec2, aggr);
    k_node<15, HS><<<nblk, 256, 0, stream>>>(hA, aggr, nn, Wl1, bl1, hB);

    // Layer 2
    hipMemsetAsync(aggr, 0, (size_t)nn * HS * sizeof(float), stream);
    k_edgeK<<<eblk, 256, 0, stream>>>(hB, ei, ne, attr, Wec1, bec1, Wec2, bec2, aggr);
    k_node<15, HS><<<nblk, 256, 0, stream>>>(hB, aggr, nn, Wl2, bl2, hA);

    // Pool + head
    hipMemsetAsync(pooled, 0, (size_t)ng * HS * sizeof(float), stream);
    k_pool<<<(int)((nn * 15 + 255) / 256), 256, 0, stream>>>(hA, batch, nn, pooled);
    k_head<<<(int)((ng + 255) / 256), 256, 0, stream>>>(pooled, ng, Wo1, bo1, Wo2, bo2, out);
}

// Round 2
// 1336.795 us; speedup vs baseline: 5.1083x; 5.1083x over previous
//
#include <hip/hip_runtime.h>
#include <math.h>

#define D_NODE 12
#define D_EDGE 4
#define HID    15
#define HS     16   // padded row stride for hidden buffers

// ---------------- CSR build: histogram of dst
__global__ __launch_bounds__(256) void k_hist(
    const int* __restrict__ ei, long long ne, int* __restrict__ cnt)
{
    long long e = (long long)blockIdx.x * 256 + threadIdx.x;
    if (e >= ne) return;
    atomicAdd(&cnt[ei[ne + e]], 1);
}

// ---------------- CSR build: single-block exclusive scan (nn up to 1024*chunk)
__global__ __launch_bounds__(1024) void k_scan(
    const int* __restrict__ cnt, int nn, int* __restrict__ off, int* __restrict__ pos)
{
    __shared__ int part[1024];
    int t = threadIdx.x;
    int chunk = (nn + 1023) / 1024;
    int beg = t * chunk;
    int end = beg + chunk; if (end > nn) end = nn;
    int s = 0;
    for (int i = beg; i < end; ++i) s += cnt[i];
    part[t] = s;
    __syncthreads();
    for (int d = 1; d < 1024; d <<= 1) {
        int v = (t >= d) ? part[t - d] : 0;
        __syncthreads();
        part[t] += v;
        __syncthreads();
    }
    int base = (t == 0) ? 0 : part[t - 1];
    for (int i = beg; i < end; ++i) {
        off[i] = base; pos[i] = base;
        base += cnt[i];
    }
    if (end == nn) off[nn] = base;   // threads past the end all write the same total
}

// ---------------- CSR build: scatter src + attr into dst-sorted order
__global__ __launch_bounds__(256) void k_scatter(
    const int* __restrict__ ei, long long ne, const float4* __restrict__ attr,
    int* __restrict__ pos, int* __restrict__ ssrc, float4* __restrict__ sattr)
{
    long long e = (long long)blockIdx.x * 256 + threadIdx.x;
    if (e >= ne) return;
    int s = ei[e];
    int d = ei[ne + e];
    int p = atomicAdd(&pos[d], 1);
    ssrc[p] = s;
    sattr[p] = attr[e];
}

// ---------------- Layer 0: per-node gather + node linear + ELU (x is 12-dim, stride 12)
__global__ __launch_bounds__(256) void k_gather0(
    const float* __restrict__ x, long long nn,
    const int* __restrict__ off, const int* __restrict__ ssrc, const float4* __restrict__ sattr,
    const float* __restrict__ Wec1, const float* __restrict__ bec1,
    const float* __restrict__ Wl, const float* __restrict__ bl,
    float* __restrict__ hout)
{
    __shared__ float sW1[48], sb1[12], sWl[15*12], sbl[15];
    int t = threadIdx.x;
    if (t < 48) sW1[t] = Wec1[t];
    if (t < 12) sb1[t] = bec1[t];
    for (int i = t; i < 15*12; i += 256) sWl[i] = Wl[i];
    if (t < 15) sbl[t] = bl[t];
    __syncthreads();
    long long n = (long long)blockIdx.x * 256 + t;
    if (n >= nn) return;
    int beg = off[n], end = off[n + 1];
    float acc[12];
#pragma unroll
    for (int i = 0; i < 12; ++i) acc[i] = 0.f;
    for (int p = beg; p < end; ++p) {
        int s = ssrc[p];
        float4 a = sattr[p];
        const float4* xs = reinterpret_cast<const float4*>(x + (long long)s * D_NODE);
        float4 x0 = xs[0], x1 = xs[1], x2 = xs[2];
        float xv[12] = {x0.x,x0.y,x0.z,x0.w, x1.x,x1.y,x1.z,x1.w, x2.x,x2.y,x2.z,x2.w};
#pragma unroll
        for (int i = 0; i < 12; ++i) {
            float ea = sb1[i] + sW1[i*4+0]*a.x + sW1[i*4+1]*a.y + sW1[i*4+2]*a.z + sW1[i*4+3]*a.w;
            acc[i] += fmaxf(xv[i] + ea, 0.f);
        }
    }
    float v[12];
#pragma unroll
    for (int j = 0; j < 12; ++j) v[j] = x[n * D_NODE + j] + acc[j];
    float* o = hout + n * HS;
#pragma unroll
    for (int i = 0; i < 15; ++i) {
        float r = sbl[i];
#pragma unroll
        for (int j = 0; j < 12; ++j) r += v[j] * sWl[i*12+j];
        o[i] = r > 0.f ? r : expm1f(r);
    }
    o[15] = 0.f;
}

// ---------------- Layers 1/2: per-node gather (recompute ea2 per edge) + node linear + ELU
template<bool POOL>
__global__ __launch_bounds__(256) void k_gatherK(
    const float* __restrict__ hin, long long nn,
    const int* __restrict__ off, const int* __restrict__ ssrc, const float4* __restrict__ sattr,
    const float* __restrict__ Wec1, const float* __restrict__ bec1,
    const float* __restrict__ Wec2, const float* __restrict__ bec2,
    const float* __restrict__ Wl, const float* __restrict__ bl,
    float* __restrict__ hout,
    const int* __restrict__ batch, float* __restrict__ pooled)
{
    __shared__ float sW1[48], sb1[12], sW2[180], sb2[15], sWl[225], sbl[15];
    int t = threadIdx.x;
    if (t < 48)  sW1[t] = Wec1[t];
    if (t < 12)  sb1[t] = bec1[t];
    if (t < 180) sW2[t] = Wec2[t];
    if (t < 15)  sb2[t] = bec2[t];
    if (t < 225) sWl[t] = Wl[t];
    if (t < 15)  sbl[t] = bl[t];
    __syncthreads();
    long long n = (long long)blockIdx.x * 256 + t;
    if (n >= nn) return;
    int beg = off[n], end = off[n + 1];
    float acc[15];
#pragma unroll
    for (int i = 0; i < 15; ++i) acc[i] = 0.f;
    for (int p = beg; p < end; ++p) {
        int s = ssrc[p];
        float4 a = sattr[p];
        float ea[12];
#pragma unroll
        for (int i = 0; i < 12; ++i)
            ea[i] = sb1[i] + sW1[i*4+0]*a.x + sW1[i*4+1]*a.y + sW1[i*4+2]*a.z + sW1[i*4+3]*a.w;
        const float4* hs = reinterpret_cast<const float4*>(hin + (long long)s * HS);
        float4 h0 = hs[0], h1 = hs[1], h2 = hs[2], h3 = hs[3];
        float hv[15] = {h0.x,h0.y,h0.z,h0.w, h1.x,h1.y,h1.z,h1.w,
                        h2.x,h2.y,h2.z,h2.w, h3.x,h3.y,h3.z};
#pragma unroll
        for (int i = 0; i < 15; ++i) {
            float e2 = sb2[i];
#pragma unroll
            for (int j = 0; j < 12; ++j) e2 += sW2[i*12+j] * ea[j];
            acc[i] += fmaxf(hv[i] + e2, 0.f);
        }
    }
    float v[15];
#pragma unroll
    for (int j = 0; j < 15; ++j) v[j] = hin[n * HS + j] + acc[j];
    float* o = hout + n * HS;
    long long pb = POOL ? (long long)batch[n] * HS : 0;
#pragma unroll
    for (int i = 0; i < 15; ++i) {
        float r = sbl[i];
#pragma unroll
        for (int j = 0; j < 15; ++j) r += v[j] * sWl[i*15+j];
        float hv2 = r > 0.f ? r : expm1f(r);
        o[i] = hv2;
        if (POOL) atomicAdd(&pooled[pb + i], hv2);
    }
    o[15] = 0.f;
}

// ---------------- Head: out = (pooled @ Wo1.T + bo1) @ Wo2.T + bo2
__global__ __launch_bounds__(256) void k_head(
    const float* __restrict__ pooled, long long ng,
    const float* __restrict__ Wo1, const float* __restrict__ bo1,
    const float* __restrict__ Wo2, const float* __restrict__ bo2,
    float* __restrict__ out)
{
    long long g = (long long)blockIdx.x * 256 + threadIdx.x;
    if (g >= ng) return;
    float p[15], m[15];
#pragma unroll
    for (int j = 0; j < 15; ++j) p[j] = pooled[g * HS + j];
#pragma unroll
    for (int i = 0; i < 15; ++i) {
        float acc = bo1[i];
#pragma unroll
        for (int j = 0; j < 15; ++j) acc += p[j] * Wo1[i * 15 + j];
        m[i] = acc;
    }
#pragma unroll
    for (int i = 0; i < 2; ++i) {
        float acc = bo2[i];
#pragma unroll
        for (int j = 0; j < 15; ++j) acc += m[j] * Wo2[i * 15 + j];
        out[g * 2 + i] = acc;
    }
}

extern "C" void kernel_launch(void* const* d_in, const int* in_sizes, int n_in,
                              void* d_out, int out_size, void* d_ws, size_t ws_size,
                              hipStream_t stream)
{
    const float* x    = (const float*)d_in[0];
    const int*   ei   = (const int*)d_in[1];
    const float* attr = (const float*)d_in[2];
    const int*   batch= (const int*)d_in[3];
    const float* Wec1 = (const float*)d_in[4];
    const float* bec1 = (const float*)d_in[5];
    const float* Wec2 = (const float*)d_in[6];
    const float* bec2 = (const float*)d_in[7];
    const float* Wl0  = (const float*)d_in[8];
    const float* bl0  = (const float*)d_in[9];
    const float* Wl1  = (const float*)d_in[10];
    const float* bl1  = (const float*)d_in[11];
    const float* Wl2  = (const float*)d_in[12];
    const float* bl2  = (const float*)d_in[13];
    const float* Wo1  = (const float*)d_in[14];
    const float* bo1  = (const float*)d_in[15];
    const float* Wo2  = (const float*)d_in[16];
    const float* bo2  = (const float*)d_in[17];

    const long long nn = in_sizes[0] / D_NODE;   // 100000
    const long long ne = in_sizes[1] / 2;        // 3200000
    const long long ng = out_size / 2;           // 1024

    // ---- workspace layout (16B-aligned chunks) ----
    char* w = (char*)d_ws;
    float4* sattr = (float4*)w;                     w += (size_t)ne * sizeof(float4);
    int*    ssrc  = (int*)w;                        w += (size_t)ne * sizeof(int);
    int*    cnt   = (int*)w;                        w += (size_t)nn * sizeof(int);
    int*    off   = (int*)w;                        w += ((size_t)nn + 1) * sizeof(int);
    int*    pos   = (int*)w;                        w += (size_t)nn * sizeof(int);
    w = (char*)(((uintptr_t)w + 15) & ~(uintptr_t)15);
    float*  hA    = (float*)w;                      w += (size_t)nn * HS * sizeof(float);
    float*  hB    = (float*)w;                      w += (size_t)nn * HS * sizeof(float);
    float*  pooled= (float*)w;
    float*  out   = (float*)d_out;

    const int eblk = (int)((ne + 255) / 256);
    const int nblk = (int)((nn + 255) / 256);

    // ---- build dst-CSR (shared by all 3 layers) ----
    hipMemsetAsync(cnt, 0, (size_t)nn * sizeof(int), stream);
    k_hist<<<eblk, 256, 0, stream>>>(ei, ne, cnt);
    k_scan<<<1, 1024, 0, stream>>>(cnt, (int)nn, off, pos);
    k_scatter<<<eblk, 256, 0, stream>>>(ei, ne, (const float4*)attr, pos, ssrc, sattr);

    // ---- layers ----
    k_gather0<<<nblk, 256, 0, stream>>>(x, nn, off, ssrc, sattr, Wec1, bec1, Wl0, bl0, hA);
    k_gatherK<false><<<nblk, 256, 0, stream>>>(hA, nn, off, ssrc, sattr,
                                               Wec1, bec1, Wec2, bec2, Wl1, bl1, hB,
                                               batch, nullptr);
    hipMemsetAsync(pooled, 0, (size_t)ng * HS * sizeof(float), stream);
    k_gatherK<true><<<nblk, 256, 0, stream>>>(hB, nn, off, ssrc, sattr,
                                              Wec1, bec1, Wec2, bec2, Wl2, bl2, hA,
                                              batch, pooled);
    k_head<<<(int)((ng + 255) / 256), 256, 0, stream>>>(pooled, ng, Wo1, bo1, Wo2, bo2, out);
}

// Round 3
// 1248.671 us; speedup vs baseline: 5.4688x; 1.0706x over previous
//
#include <hip/hip_runtime.h>
#include <math.h>

#define D_NODE 12
#define D_EDGE 4
#define HID    15
#define HS     16   // padded row stride for hidden/aggr buffers

// ---------------- CSR build: histogram of dst
__global__ __launch_bounds__(256) void k_hist(
    const int* __restrict__ ei, long long ne, int* __restrict__ cnt)
{
    long long e = (long long)blockIdx.x * 256 + threadIdx.x;
    if (e >= ne) return;
    atomicAdd(&cnt[ei[ne + e]], 1);
}

// ---------------- CSR build: single-block exclusive scan
__global__ __launch_bounds__(1024) void k_scan(
    const int* __restrict__ cnt, int nn, int* __restrict__ off, int* __restrict__ pos)
{
    __shared__ int part[1024];
    int t = threadIdx.x;
    int chunk = (nn + 1023) / 1024;
    int beg = t * chunk;
    int end = beg + chunk; if (end > nn) end = nn;
    int s = 0;
    for (int i = beg; i < end; ++i) s += cnt[i];
    part[t] = s;
    __syncthreads();
    for (int d = 1; d < 1024; d <<= 1) {
        int v = (t >= d) ? part[t - d] : 0;
        __syncthreads();
        part[t] += v;
        __syncthreads();
    }
    int base = (t == 0) ? 0 : part[t - 1];
    for (int i = beg; i < end; ++i) {
        off[i] = base; pos[i] = base;
        base += cnt[i];
    }
    if (end == nn) off[nn] = base;
}

// ---------------- CSR build: scatter (src,dst) + attr into dst-sorted order
__global__ __launch_bounds__(256) void k_scatter(
    const int* __restrict__ ei, long long ne, const float4* __restrict__ attr,
    int* __restrict__ pos, int2* __restrict__ ssd, float4* __restrict__ sattr)
{
    long long e = (long long)blockIdx.x * 256 + threadIdx.x;
    if (e >= ne) return;
    int s = ei[e];
    int d = ei[ne + e];
    int p = atomicAdd(&pos[d], 1);
    ssd[p] = make_int2(s, d);
    sattr[p] = attr[e];
}

// ---------------- Layer 0 edge kernel: edge-parallel, wave-segmented reduce into aggr
__global__ __launch_bounds__(256) void k_edge0(
    const float* __restrict__ x, long long ne,
    const int2* __restrict__ ssd, const float4* __restrict__ sattr,
    const float* __restrict__ Wec1, const float* __restrict__ bec1,
    float* __restrict__ aggr)
{
    __shared__ float sW1[48], sb1[12];
    int t = threadIdx.x;
    if (t < 48) sW1[t] = Wec1[t];
    if (t < 12) sb1[t] = bec1[t];
    __syncthreads();
    long long e = (long long)blockIdx.x * 256 + t;
    int lane = t & 63;
    int s = 0, d = -1;
    float4 a = make_float4(0.f, 0.f, 0.f, 0.f);
    if (e < ne) { int2 sd = ssd[e]; s = sd.x; d = sd.y; a = sattr[e]; }
    const float4* xs = reinterpret_cast<const float4*>(x + (long long)s * D_NODE);
    float4 x0 = xs[0], x1 = xs[1], x2 = xs[2];
    float xv[12] = {x0.x,x0.y,x0.z,x0.w, x1.x,x1.y,x1.z,x1.w, x2.x,x2.y,x2.z,x2.w};
    float msg[12];
#pragma unroll
    for (int i = 0; i < 12; ++i) {
        float ea = sb1[i] + sW1[i*4+0]*a.x + sW1[i*4+1]*a.y + sW1[i*4+2]*a.z + sW1[i*4+3]*a.w;
        msg[i] = fmaxf(xv[i] + ea, 0.f);
    }
    // backward inclusive segmented reduce (contiguous equal-d segments)
#pragma unroll
    for (int off = 1; off < 64; off <<= 1) {
        int d2 = __shfl_down(d, off, 64);
        bool take = (lane + off < 64) && (d2 == d);
#pragma unroll
        for (int i = 0; i < 12; ++i) {
            float m2 = __shfl_down(msg[i], off, 64);
            if (take) msg[i] += m2;
        }
    }
    int dprev = __shfl_up(d, 1, 64);
    bool head = (lane == 0) || (dprev != d);
    if (head && d >= 0) {
        float* ag = aggr + (long long)d * HS;
#pragma unroll
        for (int i = 0; i < 12; ++i) atomicAdd(ag + i, msg[i]);
    }
}

// ---------------- Layers 1/2 edge kernel: folded W12 = Wec2@Wec1, b12 = Wec2@bec1+bec2
__global__ __launch_bounds__(256) void k_edgeK(
    const float* __restrict__ h, long long ne,
    const int2* __restrict__ ssd, const float4* __restrict__ sattr,
    const float* __restrict__ Wec1, const float* __restrict__ bec1,
    const float* __restrict__ Wec2, const float* __restrict__ bec2,
    float* __restrict__ aggr)
{
    __shared__ float sW12[60], sb12[15];
    int t = threadIdx.x;
    if (t < 60) {
        int i = t >> 2, k = t & 3;
        float acc = 0.f;
#pragma unroll
        for (int j = 0; j < 12; ++j) acc += Wec2[i*12+j] * Wec1[j*4+k];
        sW12[t] = acc;
    }
    if (t < 15) {
        float acc = bec2[t];
#pragma unroll
        for (int j = 0; j < 12; ++j) acc += Wec2[t*12+j] * bec1[j];
        sb12[t] = acc;
    }
    __syncthreads();
    long long e = (long long)blockIdx.x * 256 + t;
    int lane = t & 63;
    int s = 0, d = -1;
    float4 a = make_float4(0.f, 0.f, 0.f, 0.f);
    if (e < ne) { int2 sd = ssd[e]; s = sd.x; d = sd.y; a = sattr[e]; }
    const float4* hs = reinterpret_cast<const float4*>(h + (long long)s * HS);
    float4 h0 = hs[0], h1 = hs[1], h2 = hs[2], h3 = hs[3];
    float hv[15] = {h0.x,h0.y,h0.z,h0.w, h1.x,h1.y,h1.z,h1.w,
                    h2.x,h2.y,h2.z,h2.w, h3.x,h3.y,h3.z};
    float msg[15];
#pragma unroll
    for (int i = 0; i < 15; ++i) {
        float e2 = sb12[i] + sW12[i*4+0]*a.x + sW12[i*4+1]*a.y + sW12[i*4+2]*a.z + sW12[i*4+3]*a.w;
        msg[i] = fmaxf(hv[i] + e2, 0.f);
    }
#pragma unroll
    for (int off = 1; off < 64; off <<= 1) {
        int d2 = __shfl_down(d, off, 64);
        bool take = (lane + off < 64) && (d2 == d);
#pragma unroll
        for (int i = 0; i < 15; ++i) {
            float m2 = __shfl_down(msg[i], off, 64);
            if (take) msg[i] += m2;
        }
    }
    int dprev = __shfl_up(d, 1, 64);
    bool head = (lane == 0) || (dprev != d);
    if (head && d >= 0) {
        float* ag = aggr + (long long)d * HS;
#pragma unroll
        for (int i = 0; i < 15; ++i) atomicAdd(ag + i, msg[i]);
    }
}

// ---------------- Node update: hout = elu((hin + aggr) @ W.T + b); optional pool-only tail
template<int IN, int INS, bool POOL, bool STORE>
__global__ __launch_bounds__(256) void k_node(
    const float* __restrict__ hin, const float* __restrict__ aggr, long long nn,
    const float* __restrict__ W, const float* __restrict__ b,
    float* __restrict__ hout,
    const int* __restrict__ batch, float* __restrict__ pooled)
{
    __shared__ float sW[15 * IN];
    __shared__ float sb[15];
    int t = threadIdx.x;
    for (int i = t; i < 15 * IN; i += 256) sW[i] = W[i];
    if (t < 15) sb[t] = b[t];
    __syncthreads();
    long long n = (long long)blockIdx.x * 256 + t;
    if (n >= nn) return;
    float v[IN];
#pragma unroll
    for (int j = 0; j < IN; ++j)
        v[j] = hin[n * INS + j] + aggr[n * HS + j];
    long long pb = POOL ? (long long)batch[n] * HS : 0;
    float* o = STORE ? (hout + n * HS) : nullptr;
#pragma unroll
    for (int i = 0; i < 15; ++i) {
        float acc = sb[i];
#pragma unroll
        for (int j = 0; j < IN; ++j) acc += v[j] * sW[i * IN + j];
        float r = acc > 0.f ? acc : expm1f(acc);
        if (STORE) o[i] = r;
        if (POOL) atomicAdd(&pooled[pb + i], r);
    }
    if (STORE) o[15] = 0.f;
}

// ---------------- Head
__global__ __launch_bounds__(256) void k_head(
    const float* __restrict__ pooled, long long ng,
    const float* __restrict__ Wo1, const float* __restrict__ bo1,
    const float* __restrict__ Wo2, const float* __restrict__ bo2,
    float* __restrict__ out)
{
    long long g = (long long)blockIdx.x * 256 + threadIdx.x;
    if (g >= ng) return;
    float p[15], m[15];
#pragma unroll
    for (int j = 0; j < 15; ++j) p[j] = pooled[g * HS + j];
#pragma unroll
    for (int i = 0; i < 15; ++i) {
        float acc = bo1[i];
#pragma unroll
        for (int j = 0; j < 15; ++j) acc += p[j] * Wo1[i * 15 + j];
        m[i] = acc;
    }
#pragma unroll
    for (int i = 0; i < 2; ++i) {
        float acc = bo2[i];
#pragma unroll
        for (int j = 0; j < 15; ++j) acc += m[j] * Wo2[i * 15 + j];
        out[g * 2 + i] = acc;
    }
}

extern "C" void kernel_launch(void* const* d_in, const int* in_sizes, int n_in,
                              void* d_out, int out_size, void* d_ws, size_t ws_size,
                              hipStream_t stream)
{
    const float* x    = (const float*)d_in[0];
    const int*   ei   = (const int*)d_in[1];
    const float* attr = (const float*)d_in[2];
    const int*   batch= (const int*)d_in[3];
    const float* Wec1 = (const float*)d_in[4];
    const float* bec1 = (const float*)d_in[5];
    const float* Wec2 = (const float*)d_in[6];
    const float* bec2 = (const float*)d_in[7];
    const float* Wl0  = (const float*)d_in[8];
    const float* bl0  = (const float*)d_in[9];
    const float* Wl1  = (const float*)d_in[10];
    const float* bl1  = (const float*)d_in[11];
    const float* Wl2  = (const float*)d_in[12];
    const float* bl2  = (const float*)d_in[13];
    const float* Wo1  = (const float*)d_in[14];
    const float* bo1  = (const float*)d_in[15];
    const float* Wo2  = (const float*)d_in[16];
    const float* bo2  = (const float*)d_in[17];

    const long long nn = in_sizes[0] / D_NODE;   // 100000
    const long long ne = in_sizes[1] / 2;        // 3200000
    const long long ng = out_size / 2;           // 1024

    // ---- workspace layout ----
    char* w = (char*)d_ws;
    float4* sattr = (float4*)w;                   w += (size_t)ne * sizeof(float4);
    int2*   ssd   = (int2*)w;                     w += (size_t)ne * sizeof(int2);
    int*    cnt   = (int*)w;                      w += (size_t)nn * sizeof(int);
    int*    off   = (int*)w;                      w += ((size_t)nn + 1) * sizeof(int);
    int*    pos   = (int*)w;                      w += (size_t)nn * sizeof(int);
    w = (char*)(((uintptr_t)w + 15) & ~(uintptr_t)15);
    float*  aggr  = (float*)w;                    w += (size_t)nn * HS * sizeof(float);
    float*  hA    = (float*)w;                    w += (size_t)nn * HS * sizeof(float);
    float*  hB    = (float*)w;                    w += (size_t)nn * HS * sizeof(float);
    float*  pooled= (float*)w;
    float*  out   = (float*)d_out;

    const int eblk = (int)((ne + 255) / 256);
    const int nblk = (int)((nn + 255) / 256);

    // ---- build dst-CSR (shared by all 3 layers) ----
    hipMemsetAsync(cnt, 0, (size_t)nn * sizeof(int), stream);
    k_hist<<<eblk, 256, 0, stream>>>(ei, ne, cnt);
    k_scan<<<1, 1024, 0, stream>>>(cnt, (int)nn, off, pos);
    k_scatter<<<eblk, 256, 0, stream>>>(ei, ne, (const float4*)attr, pos, ssd, sattr);

    // ---- layer 0 ----
    hipMemsetAsync(aggr, 0, (size_t)nn * HS * sizeof(float), stream);
    k_edge0<<<eblk, 256, 0, stream>>>(x, ne, ssd, sattr, Wec1, bec1, aggr);
    k_node<12, 12, false, true><<<nblk, 256, 0, stream>>>(x, aggr, nn, Wl0, bl0, hA, nullptr, nullptr);

    // ---- layer 1 ----
    hipMemsetAsync(aggr, 0, (size_t)nn * HS * sizeof(float), stream);
    k_edgeK<<<eblk, 256, 0, stream>>>(hA, ne, ssd, sattr, Wec1, bec1, Wec2, bec2, aggr);
    k_node<15, HS, false, true><<<nblk, 256, 0, stream>>>(hA, aggr, nn, Wl1, bl1, hB, nullptr, nullptr);

    // ---- layer 2 (pool fused into node kernel, h not stored) ----
    hipMemsetAsync(aggr, 0, (size_t)nn * HS * sizeof(float), stream);
    k_edgeK<<<eblk, 256, 0, stream>>>(hB, ne, ssd, sattr, Wec1, bec1, Wec2, bec2, aggr);
    hipMemsetAsync(pooled, 0, (size_t)ng * HS * sizeof(float), stream);
    k_node<15, HS, true, false><<<nblk, 256, 0, stream>>>(hB, aggr, nn, Wl2, bl2, nullptr, batch, pooled);

    // ---- head ----
    k_head<<<(int)((ng + 255) / 256), 256, 0, stream>>>(pooled, ng, Wo1, bo1, Wo2, bo2, out);
}

// Round 4
// 1076.824 us; speedup vs baseline: 6.3416x; 1.1596x over previous
//
#include <hip/hip_runtime.h>
#include <math.h>

#define D_NODE 12
#define HS     16     // padded row stride for hidden buffers
#define BSH    7      // bucket shift: 128 nodes per bucket
#define BSZ    128
#define CHUNK  4096   // edges per partition block (P1/P2)
#define MAXNB  1024   // max buckets supported (nn <= 131072)

// ---------------- P1: per-(block,bucket) histogram of dst
__global__ __launch_bounds__(256) void k_p1(
    const int* __restrict__ ei, long long ne, int NB, int* __restrict__ M)
{
    __shared__ int cnt[MAXNB];
    int t = threadIdx.x;
    for (int k = t; k < NB; k += 256) cnt[k] = 0;
    __syncthreads();
    long long beg = (long long)blockIdx.x * CHUNK;
    long long end = beg + CHUNK; if (end > ne) end = ne;
    for (long long e = beg + t; e < end; e += 256)
        atomicAdd(&cnt[ei[ne + e] >> BSH], 1);
    __syncthreads();
    int* row = M + (long long)blockIdx.x * NB;
    for (int k = t; k < NB; k += 256) row[k] = cnt[k];
}

// ---------------- per-bucket column scan over blocks: M[b][k] -> exclusive prefix; tot[k] = column total
__global__ __launch_bounds__(256) void k_colscan(
    int* __restrict__ M, int nblk, int NB, int* __restrict__ tot)
{
    __shared__ int sums[256];
    int k = blockIdx.x;
    int t = threadIdx.x;
    int v[4]; int s = 0;                       // supports nblk <= 1024
#pragma unroll
    for (int j = 0; j < 4; ++j) {
        int b = t * 4 + j;
        v[j] = (b < nblk) ? M[(long long)b * NB + k] : 0;
        s += v[j];
    }
    sums[t] = s;
    __syncthreads();
    for (int d = 1; d < 256; d <<= 1) {
        int u = (t >= d) ? sums[t - d] : 0;
        __syncthreads();
        sums[t] += u;
        __syncthreads();
    }
    int base = (t == 0) ? 0 : sums[t - 1];
#pragma unroll
    for (int j = 0; j < 4; ++j) {
        int b = t * 4 + j;
        if (b < nblk) { M[(long long)b * NB + k] = base; base += v[j]; }
    }
    if (t == 255) tot[k] = sums[255];
}

// ---------------- tiny scan of bucket totals -> bucket bases bb[0..NB]
__global__ __launch_bounds__(1024) void k_bb(
    const int* __restrict__ tot, int NB, int* __restrict__ bb)
{
    __shared__ int part[1024];
    int t = threadIdx.x;
    part[t] = (t < NB) ? tot[t] : 0;
    __syncthreads();
    for (int d = 1; d < 1024; d <<= 1) {
        int v = (t >= d) ? part[t - d] : 0;
        __syncthreads();
        part[t] += v;
        __syncthreads();
    }
    if (t < NB) bb[t] = (t == 0) ? 0 : part[t - 1];
    if (t == NB - 1) bb[NB] = part[t];
}

// ---------------- P2: scatter edges into bucket-grouped order (LDS-ranked, no global atomics)
__global__ __launch_bounds__(256) void k_p2(
    const int* __restrict__ ei, long long ne, const float4* __restrict__ attr,
    const int* __restrict__ M, const int* __restrict__ bb, int NB,
    unsigned* __restrict__ sp, float4* __restrict__ sattr)
{
    __shared__ int cnt[MAXNB];
    int t = threadIdx.x;
    const int* row = M + (long long)blockIdx.x * NB;
    for (int k = t; k < NB; k += 256) cnt[k] = bb[k] + row[k];
    __syncthreads();
    long long beg = (long long)blockIdx.x * CHUNK;
    long long end = beg + CHUNK; if (end > ne) end = ne;
    for (long long e = beg + t; e < end; e += 256) {
        int s = ei[e];
        int d = ei[ne + e];
        float4 a = attr[e];
        int k = d >> BSH;
        int p = atomicAdd(&cnt[k], 1);
        sp[p] = (unsigned)s | ((unsigned)(d & (BSZ - 1)) << 20);
        sattr[p] = a;
    }
}

// ---------------- Layer 0: bucket-block edge aggregation (LDS) + fused node linear + ELU
__global__ __launch_bounds__(256) void k_layer0(
    const float* __restrict__ x, long long nn,
    const int* __restrict__ bb, const unsigned* __restrict__ sp, const float4* __restrict__ sattr,
    const float* __restrict__ Wec1, const float* __restrict__ bec1,
    const float* __restrict__ Wl, const float* __restrict__ bl,
    float* __restrict__ hout)
{
    __shared__ float acc[12 * BSZ];
    __shared__ float sW1[48], sb1[12], sWl[180], sbl[15];
    int t = threadIdx.x;
    if (t < 48)  sW1[t] = Wec1[t];
    if (t < 12)  sb1[t] = bec1[t];
    if (t < 180) sWl[t] = Wl[t];
    if (t < 15)  sbl[t] = bl[t];
    for (int i = t; i < 12 * BSZ; i += 256) acc[i] = 0.f;
    __syncthreads();
    int k = blockIdx.x;
    int beg = bb[k], end = bb[k + 1];
    for (int e = beg + t; e < end; e += 256) {
        unsigned pk = sp[e];
        int s = pk & 0xFFFFF;
        int ld = pk >> 20;
        float4 a = sattr[e];
        const float4* xs = reinterpret_cast<const float4*>(x + (long long)s * D_NODE);
        float4 x0 = xs[0], x1 = xs[1], x2 = xs[2];
        float xv[12] = {x0.x,x0.y,x0.z,x0.w, x1.x,x1.y,x1.z,x1.w, x2.x,x2.y,x2.z,x2.w};
#pragma unroll
        for (int i = 0; i < 12; ++i) {
            float ea = sb1[i] + sW1[i*4+0]*a.x + sW1[i*4+1]*a.y + sW1[i*4+2]*a.z + sW1[i*4+3]*a.w;
            atomicAdd(&acc[i * BSZ + ld], fmaxf(xv[i] + ea, 0.f));
        }
    }
    __syncthreads();
    long long n = (long long)k * BSZ + t;
    if (t < BSZ && n < nn) {
        float v[12];
#pragma unroll
        for (int j = 0; j < 12; ++j) v[j] = x[n * D_NODE + j] + acc[j * BSZ + t];
        float* o = hout + n * HS;
#pragma unroll
        for (int i = 0; i < 15; ++i) {
            float r = sbl[i];
#pragma unroll
            for (int j = 0; j < 12; ++j) r += v[j] * sWl[i * 12 + j];
            o[i] = r > 0.f ? r : expm1f(r);
        }
        o[15] = 0.f;
    }
}

// ---------------- Layers 1/2: folded edge transform, LDS aggregation, fused node linear + ELU (+pool)
template<bool POOL, bool STORE>
__global__ __launch_bounds__(256) void k_layerK(
    const float* __restrict__ h, long long nn,
    const int* __restrict__ bb, const unsigned* __restrict__ sp, const float4* __restrict__ sattr,
    const float* __restrict__ Wec1, const float* __restrict__ bec1,
    const float* __restrict__ Wec2, const float* __restrict__ bec2,
    const float* __restrict__ Wl, const float* __restrict__ bl,
    float* __restrict__ hout, const int* __restrict__ batch, float* __restrict__ pooled)
{
    __shared__ float acc[15 * BSZ];
    __shared__ float sW12[60], sb12[15], sWl[225], sbl[15];
    int t = threadIdx.x;
    if (t < 60) {                       // fold W12 = Wec2 @ Wec1  (15x4)
        int i = t >> 2, kk = t & 3;
        float a = 0.f;
#pragma unroll
        for (int j = 0; j < 12; ++j) a += Wec2[i*12+j] * Wec1[j*4+kk];
        sW12[t] = a;
    }
    if (t < 15) {                       // b12 = Wec2 @ bec1 + bec2
        float a = bec2[t];
#pragma unroll
        for (int j = 0; j < 12; ++j) a += Wec2[t*12+j] * bec1[j];
        sb12[t] = a;
    }
    if (t < 225) sWl[t] = Wl[t];
    if (t < 15)  sbl[t] = bl[t];
    for (int i = t; i < 15 * BSZ; i += 256) acc[i] = 0.f;
    __syncthreads();
    int k = blockIdx.x;
    int beg = bb[k], end = bb[k + 1];
    for (int e = beg + t; e < end; e += 256) {
        unsigned pk = sp[e];
        int s = pk & 0xFFFFF;
        int ld = pk >> 20;
        float4 a = sattr[e];
        const float4* hs = reinterpret_cast<const float4*>(h + (long long)s * HS);
        float4 h0 = hs[0], h1 = hs[1], h2 = hs[2], h3 = hs[3];
        float hv[15] = {h0.x,h0.y,h0.z,h0.w, h1.x,h1.y,h1.z,h1.w,
                        h2.x,h2.y,h2.z,h2.w, h3.x,h3.y,h3.z};
#pragma unroll
        for (int i = 0; i < 15; ++i) {
            float e2 = sb12[i] + sW12[i*4+0]*a.x + sW12[i*4+1]*a.y + sW12[i*4+2]*a.z + sW12[i*4+3]*a.w;
            atomicAdd(&acc[i * BSZ + ld], fmaxf(hv[i] + e2, 0.f));
        }
    }
    __syncthreads();
    long long n = (long long)k * BSZ + t;
    if (t < BSZ && n < nn) {
        float v[15];
#pragma unroll
        for (int j = 0; j < 15; ++j) v[j] = h[n * HS + j] + acc[j * BSZ + t];
        float* o = STORE ? (hout + n * HS) : nullptr;
        long long pb = POOL ? (long long)batch[n] * HS : 0;
#pragma unroll
        for (int i = 0; i < 15; ++i) {
            float r = sbl[i];
#pragma unroll
            for (int j = 0; j < 15; ++j) r += v[j] * sWl[i * 15 + j];
            float hv2 = r > 0.f ? r : expm1f(r);
            if (STORE) o[i] = hv2;
            if (POOL) atomicAdd(&pooled[pb + i], hv2);
        }
        if (STORE) o[15] = 0.f;
    }
}

// ---------------- Head
__global__ __launch_bounds__(256) void k_head(
    const float* __restrict__ pooled, long long ng,
    const float* __restrict__ Wo1, const float* __restrict__ bo1,
    const float* __restrict__ Wo2, const float* __restrict__ bo2,
    float* __restrict__ out)
{
    long long g = (long long)blockIdx.x * 256 + threadIdx.x;
    if (g >= ng) return;
    float p[15], m[15];
#pragma unroll
    for (int j = 0; j < 15; ++j) p[j] = pooled[g * HS + j];
#pragma unroll
    for (int i = 0; i < 15; ++i) {
        float acc = bo1[i];
#pragma unroll
        for (int j = 0; j < 15; ++j) acc += p[j] * Wo1[i * 15 + j];
        m[i] = acc;
    }
#pragma unroll
    for (int i = 0; i < 2; ++i) {
        float acc = bo2[i];
#pragma unroll
        for (int j = 0; j < 15; ++j) acc += m[j] * Wo2[i * 15 + j];
        out[g * 2 + i] = acc;
    }
}

extern "C" void kernel_launch(void* const* d_in, const int* in_sizes, int n_in,
                              void* d_out, int out_size, void* d_ws, size_t ws_size,
                              hipStream_t stream)
{
    const float* x    = (const float*)d_in[0];
    const int*   ei   = (const int*)d_in[1];
    const float* attr = (const float*)d_in[2];
    const int*   batch= (const int*)d_in[3];
    const float* Wec1 = (const float*)d_in[4];
    const float* bec1 = (const float*)d_in[5];
    const float* Wec2 = (const float*)d_in[6];
    const float* bec2 = (const float*)d_in[7];
    const float* Wl0  = (const float*)d_in[8];
    const float* bl0  = (const float*)d_in[9];
    const float* Wl1  = (const float*)d_in[10];
    const float* bl1  = (const float*)d_in[11];
    const float* Wl2  = (const float*)d_in[12];
    const float* bl2  = (const float*)d_in[13];
    const float* Wo1  = (const float*)d_in[14];
    const float* bo1  = (const float*)d_in[15];
    const float* Wo2  = (const float*)d_in[16];
    const float* bo2  = (const float*)d_in[17];

    const long long nn = in_sizes[0] / D_NODE;   // 100000
    const long long ne = in_sizes[1] / 2;        // 3200000
    const long long ng = out_size / 2;           // 1024

    const int NB   = (int)((nn + BSZ - 1) >> BSH);           // 782
    const int nblk = (int)((ne + CHUNK - 1) / CHUNK);        // 782

    // ---- workspace layout ----
    char* w = (char*)d_ws;
    float4*   sattr = (float4*)w;                 w += (size_t)ne * sizeof(float4);
    unsigned* sp    = (unsigned*)w;               w += (size_t)ne * sizeof(unsigned);
    int*      M     = (int*)w;                    w += (size_t)nblk * NB * sizeof(int);
    int*      tot   = (int*)w;                    w += (size_t)NB * sizeof(int);
    int*      bb    = (int*)w;                    w += ((size_t)NB + 1) * sizeof(int);
    w = (char*)(((uintptr_t)w + 15) & ~(uintptr_t)15);
    float*    hA    = (float*)w;                  w += (size_t)nn * HS * sizeof(float);
    float*    hB    = (float*)w;                  w += (size_t)nn * HS * sizeof(float);
    float*    pooled= (float*)w;
    float*    out   = (float*)d_out;

    // ---- bucket-grouping build (shared by all 3 layers) ----
    k_p1<<<nblk, 256, 0, stream>>>(ei, ne, NB, M);
    k_colscan<<<NB, 256, 0, stream>>>(M, nblk, NB, tot);
    k_bb<<<1, 1024, 0, stream>>>(tot, NB, bb);
    k_p2<<<nblk, 256, 0, stream>>>(ei, ne, (const float4*)attr, M, bb, NB, sp, sattr);

    // ---- layers (edge aggregation + node update fused per bucket) ----
    k_layer0<<<NB, 256, 0, stream>>>(x, nn, bb, sp, sattr, Wec1, bec1, Wl0, bl0, hA);
    k_layerK<false, true><<<NB, 256, 0, stream>>>(hA, nn, bb, sp, sattr,
        Wec1, bec1, Wec2, bec2, Wl1, bl1, hB, nullptr, nullptr);
    hipMemsetAsync(pooled, 0, (size_t)ng * HS * sizeof(float), stream);
    k_layerK<true, false><<<NB, 256, 0, stream>>>(hB, nn, bb, sp, sattr,
        Wec1, bec1, Wec2, bec2, Wl2, bl2, nullptr, batch, pooled);

    // ---- head ----
    k_head<<<(int)((ng + 255) / 256), 256, 0, stream>>>(pooled, ng, Wo1, bo1, Wo2, bo2, out);
}